// Round 6
// baseline (16.694 us; speedup 1.0000x reference)
//
#include <hip/hip_runtime.h>

// P=40000, DEG=16, CI=CO=16.
// Single kernel, no workspace. Contraction order:
//   h[p][d][i] = sum_n r[p,n,d] * feat[nbr(p,n)][i]     (edge loop: feat only, L2-resident)
//   out[p][o]  = sum_d sum_i W[d][o][i] * h[p][d][i]    (per point, in registers)
// Block = 256 threads = 64 points x 4 lanes (i-quad). Per lane:
//   Phase A: 16x dwordx4 feat gathers, 12 FMA chains -> h[3][4] in regs.
//   Phase B: partial out[16] over own i-quad (W via ds_read_b128 broadcast),
//            2x shfl_xor quad-reduce, one dwordx4 store. No second barrier.

__global__ __launch_bounds__(256) void k_conv(const float* __restrict__ feat,
                                              const float* __restrict__ radii,
                                              const float* __restrict__ W,
                                              const int* __restrict__ bs,
                                              float* __restrict__ out,
                                              int P) {
    __shared__ float s_W[768];        // raw copy of W [3][16][16]
    __shared__ int   s_nbr[64][17];   // +1 pad: 17 odd -> 16 lp hit 16 banks
    __shared__ float s_r[64][49];     // +1 pad: 49 odd -> conflict-free reads

    const int tid = threadIdx.x;
    const int pbase = blockIdx.x * 64;
    const int lp = tid >> 2;          // local point 0..63
    const int lq = tid & 3;           // i-quad (phase A) / store-quad (phase B)

    // --- stage W: 192 float4 ---
    if (tid < 192) {
        reinterpret_cast<float4*>(s_W)[tid] = reinterpret_cast<const float4*>(W)[tid];
    }
    // --- stage neighbor indices: 1024 entries ---
    for (int t = tid; t < 1024; t += 256) {
        const int l = t >> 4, n = t & 15;
        const int p = pbase + l;
        s_nbr[l][n] = (p < P) ? bs[(size_t)p * 17 + 1 + n] : 0;
    }
    // --- stage radii: 3072 floats, coalesced global reads, padded LDS dest ---
    {
        const size_t lim = (size_t)P * 48;
        for (int t = tid; t < 3072; t += 256) {
            const size_t gi = (size_t)pbase * 48 + t;
            const int l = t / 48;
            const int c = t - l * 48;
            s_r[l][c] = (gi < lim) ? radii[gi] : 0.f;
        }
    }
    __syncthreads();

    // --- neighbor indices for this point into registers (static-indexed) ---
    int nb[16];
#pragma unroll
    for (int n = 0; n < 16; ++n) nb[n] = s_nbr[lp][n];

    // --- Phase A: h[d][i-quad] accumulation ---
    float4 h0 = {0.f, 0.f, 0.f, 0.f};
    float4 h1 = {0.f, 0.f, 0.f, 0.f};
    float4 h2 = {0.f, 0.f, 0.f, 0.f};
    const float4* feat4 = reinterpret_cast<const float4*>(feat);
#pragma unroll
    for (int n = 0; n < 16; ++n) {
        const float4 f = feat4[(size_t)nb[n] * 4 + lq];   // 16B, 4 lanes cover the row
        const float r0 = s_r[lp][n * 3 + 0];
        const float r1 = s_r[lp][n * 3 + 1];
        const float r2 = s_r[lp][n * 3 + 2];
        h0.x += r0 * f.x; h0.y += r0 * f.y; h0.z += r0 * f.z; h0.w += r0 * f.w;
        h1.x += r1 * f.x; h1.y += r1 * f.y; h1.z += r1 * f.z; h1.w += r1 * f.w;
        h2.x += r2 * f.x; h2.y += r2 * f.y; h2.z += r2 * f.z; h2.w += r2 * f.w;
    }

    // --- Phase B: po[o] = sum_d sum_{i in quad} W[d][o][i] * h[d][i] ---
    const float4* sW4 = reinterpret_cast<const float4*>(s_W);
    float po[16];
#pragma unroll
    for (int o = 0; o < 16; ++o) po[o] = 0.f;
#pragma unroll
    for (int d = 0; d < 3; ++d) {
        const float4 hd = (d == 0) ? h0 : (d == 1) ? h1 : h2;
#pragma unroll
        for (int o = 0; o < 16; ++o) {
            // W[d][o][lq*4 .. lq*4+3], float4 unit index = d*64 + o*4 + lq
            const float4 w = sW4[d * 64 + o * 4 + lq];
            po[o] += w.x * hd.x + w.y * hd.y + w.z * hd.z + w.w * hd.w;
        }
    }
    // quad-reduce (lanes differing in bits 0-1 share a point)
#pragma unroll
    for (int o = 0; o < 16; ++o) {
        po[o] += __shfl_xor(po[o], 1, 64);
        po[o] += __shfl_xor(po[o], 2, 64);
    }

    const int p = pbase + lp;
    if (p < P) {
        float4 v;   // static-indexed select of this lane's o-quad (no scratch)
        if (lq == 0)      { v.x = po[0];  v.y = po[1];  v.z = po[2];  v.w = po[3];  }
        else if (lq == 1) { v.x = po[4];  v.y = po[5];  v.z = po[6];  v.w = po[7];  }
        else if (lq == 2) { v.x = po[8];  v.y = po[9];  v.z = po[10]; v.w = po[11]; }
        else              { v.x = po[12]; v.y = po[13]; v.z = po[14]; v.w = po[15]; }
        reinterpret_cast<float4*>(out)[(size_t)p * 4 + lq] = v;
    }
}

extern "C" void kernel_launch(void* const* d_in, const int* in_sizes, int n_in,
                              void* d_out, int out_size, void* d_ws, size_t ws_size,
                              hipStream_t stream) {
    const float* feat  = (const float*)d_in[0];   // [P,16] f32
    const float* radii = (const float*)d_in[1];   // [E,3]  f32
    const float* W     = (const float*)d_in[2];   // [3,16,16] f32
    const int*   bs    = (const int*)d_in[3];     // [P,17] i32
    float* out = (float*)d_out;                   // [P,16] f32

    const int P = in_sizes[0] / 16;
    const int grid = (P + 63) / 64;
    k_conv<<<grid, 256, 0, stream>>>(feat, radii, W, bs, out, P);
}

// Round 7
// 12.309 us; speedup vs baseline: 1.3562x; 1.3562x over previous
//
#include <hip/hip_runtime.h>

// P=40000, DEG=16, CI=CO=16.
// Single kernel, no workspace. Contraction order:
//   h[p][d][i] = sum_n r[p,n,d] * feat[nbr(p,n)][i]     (edge loop: feat only, L2-resident)
//   out[p][o]  = sum_d sum_i W[d][o][i] * h[p][d][i]    (per point)
// Block = 256 threads = 16 points x 16 lanes (li = i in phase A, o in phase B).
// LDS-instruction-minimized: nbr/radii preloaded to VGPRs via b128 broadcasts,
// phase B reads W (padded [o][52]) and h as float4. ~48 LDS instrs/thread vs 160.

__global__ __launch_bounds__(256) void k_conv(const float* __restrict__ feat,
                                              const float* __restrict__ radii,
                                              const float* __restrict__ W,
                                              const int* __restrict__ bs,
                                              float* __restrict__ out,
                                              int P) {
    __shared__ __align__(16) float s_Wt[16][52];  // [o][d*16+i], pad 48->52 (bank spread)
    __shared__ __align__(16) int   s_nbr[16][16]; // [lp][n], 64B rows
    __shared__ __align__(16) float s_r[16][48];   // [lp][n*3+d], 192B rows
    __shared__ __align__(16) float s_h[16][48];   // [lp][d*16+i]

    const int tid = threadIdx.x;
    const int pbase = blockIdx.x * 16;
    const int lp = tid >> 4;          // local point 0..15
    const int li = tid & 15;          // i (phase A) / o (phase B)

    // --- stage W transposed: Wt[o][d*16+i] = W[d][o][i] ---
    for (int t = tid; t < 768; t += 256) {
        const int d = t >> 8, o = (t >> 4) & 15, i = t & 15;
        s_Wt[o][d * 16 + i] = W[t];
    }
    // --- stage neighbor indices ---
    {
        const int p = pbase + lp;
        s_nbr[lp][li] = (p < P) ? bs[(size_t)p * 17 + 1 + li] : 0;
    }
    // --- stage radii: 768 floats = 192 float4, coalesced ---
    if (tid < 192) {
        const size_t gi4  = (size_t)pbase * 12 + tid;   // float4 units
        const size_t lim4 = (size_t)P * 12;
        float4 v = {0.f, 0.f, 0.f, 0.f};
        if (gi4 < lim4) v = reinterpret_cast<const float4*>(radii)[gi4];
        reinterpret_cast<float4*>(&s_r[0][0])[tid] = v;
    }
    __syncthreads();

    // --- preload neighbor row (4x b128, same-address broadcast per group) ---
    int nb[16];
    {
        const int4* nb4 = reinterpret_cast<const int4*>(&s_nbr[lp][0]);
#pragma unroll
        for (int j = 0; j < 4; ++j) {
            const int4 v = nb4[j];
            nb[j*4+0] = v.x; nb[j*4+1] = v.y; nb[j*4+2] = v.z; nb[j*4+3] = v.w;
        }
    }
    // --- preload radii row (12x b128, same-address broadcast per group) ---
    float r[48];
    {
        const float4* r4 = reinterpret_cast<const float4*>(&s_r[lp][0]);
#pragma unroll
        for (int j = 0; j < 12; ++j) {
            const float4 v = r4[j];
            r[j*4+0] = v.x; r[j*4+1] = v.y; r[j*4+2] = v.z; r[j*4+3] = v.w;
        }
    }

    // --- Phase A: h[d] for this thread's i = li ---
    float h0 = 0.f, h1 = 0.f, h2 = 0.f;
#pragma unroll
    for (int n = 0; n < 16; ++n) {
        const float fv = feat[((size_t)nb[n] << 4) + li];  // 64B coalesced per group
        h0 += r[n * 3 + 0] * fv;
        h1 += r[n * 3 + 1] * fv;
        h2 += r[n * 3 + 2] * fv;
    }
    s_h[lp][li]      = h0;
    s_h[lp][16 + li] = h1;
    s_h[lp][32 + li] = h2;
    __syncthreads();

    // --- Phase B: out[p][o=li] = sum_c Wt[li][c] * h[lp][c], c = d*16+i ---
    float acc = 0.f;
    {
        const float4* w4 = reinterpret_cast<const float4*>(&s_Wt[li][0]);
        const float4* h4 = reinterpret_cast<const float4*>(&s_h[lp][0]);
#pragma unroll
        for (int j = 0; j < 12; ++j) {
            const float4 w = w4[j];
            const float4 h = h4[j];
            acc += w.x * h.x + w.y * h.y + w.z * h.z + w.w * h.w;
        }
    }
    const int p = pbase + lp;
    if (p < P) out[(size_t)p * 16 + li] = acc;
}

extern "C" void kernel_launch(void* const* d_in, const int* in_sizes, int n_in,
                              void* d_out, int out_size, void* d_ws, size_t ws_size,
                              hipStream_t stream) {
    const float* feat  = (const float*)d_in[0];   // [P,16] f32
    const float* radii = (const float*)d_in[1];   // [E,3]  f32
    const float* W     = (const float*)d_in[2];   // [3,16,16] f32
    const int*   bs    = (const int*)d_in[3];     // [P,17] i32
    float* out = (float*)d_out;                   // [P,16] f32

    const int P = in_sizes[0] / 16;
    const int grid = (P + 15) / 16;
    k_conv<<<grid, 256, 0, stream>>>(feat, radii, W, bs, out, P);
}